// Round 1
// baseline (417.567 us; speedup 1.0000x reference)
//
#include <hip/hip_runtime.h>
#include <math.h>

// EulerRosenbrockModel: B=512, D=256, HID=1024, H_STEP=0.01
// out_b = (I - c*J_b)^{-1} (I + d*J_b) v_b,  c=h/3, d=h/6
// J_b = W2 diag(s_b) W1,  s_b = 1 - tanh^2(W1 y_b + b1),  v_b = W2 tanh(...) + b2
// ||c*J|| ~ 0.015 -> Neumann series to (cJ)^3, J applied via low-rank factors.

#define B_SZ   512
#define D_SZ   256
#define HID_SZ 1024

enum { EPI_TANH = 0, EPI_BIAS = 1, EPI_MULS = 2, EPI_AXPY_SET = 3, EPI_AXPY_ADD = 4 };

// C[M,N] = A[M,K] @ B[N,K]^T  (both row-major, dot of rows), with epilogues.
template<int EPI, int BM, int BN, int BK, int TM, int TN>
__global__ __launch_bounds__(256)
void gemm_nt(const float* __restrict__ A, const float* __restrict__ Bm,
             int M, int N, int K,
             const float* __restrict__ bias,  // EPI_TANH / EPI_BIAS
             const float* __restrict__ Sp,    // EPI_MULS: elementwise multiplier (M,N)
             const float* __restrict__ ADD,   // EPI_AXPY_SET: additive term (M,N)
             float alpha,
             float* __restrict__ O1,          // primary output
             float* __restrict__ O2)          // secondary (S for TANH, OUT for AXPY)
{
    __shared__ float As[BK][BM + 1];
    __shared__ float Bs[BK][BN + 1];
    const int bm = blockIdx.y * BM;
    const int bn = blockIdx.x * BN;
    const int tid = threadIdx.x;
    constexpr int TX = BN / TN;  // threads along N; (BM/TM)*(BN/TN) == 256
    const int ty = tid / TX;
    const int tx = tid % TX;

    float acc[TM][TN];
#pragma unroll
    for (int i = 0; i < TM; ++i)
#pragma unroll
        for (int j = 0; j < TN; ++j) acc[i][j] = 0.f;

    for (int k0 = 0; k0 < K; k0 += BK) {
        constexpr int LA = (BM * BK) / 256;
#pragma unroll
        for (int l = 0; l < LA; ++l) {
            int idx = l * 256 + tid;
            int r = idx / BK, kk = idx % BK;
            As[kk][r] = A[(size_t)(bm + r) * K + k0 + kk];
        }
        constexpr int LB = (BN * BK) / 256;
#pragma unroll
        for (int l = 0; l < LB; ++l) {
            int idx = l * 256 + tid;
            int r = idx / BK, kk = idx % BK;
            Bs[kk][r] = Bm[(size_t)(bn + r) * K + k0 + kk];
        }
        __syncthreads();
#pragma unroll
        for (int kk = 0; kk < BK; ++kk) {
            float a[TM], b[TN];
#pragma unroll
            for (int i = 0; i < TM; ++i) a[i] = As[kk][ty * TM + i];
#pragma unroll
            for (int j = 0; j < TN; ++j) b[j] = Bs[kk][tx * TN + j];
#pragma unroll
            for (int i = 0; i < TM; ++i)
#pragma unroll
                for (int j = 0; j < TN; ++j)
                    acc[i][j] = fmaf(a[i], b[j], acc[i][j]);
        }
        __syncthreads();
    }

#pragma unroll
    for (int i = 0; i < TM; ++i) {
        int row = bm + ty * TM + i;
#pragma unroll
        for (int j = 0; j < TN; ++j) {
            int col = bn + tx * TN + j;
            size_t idx = (size_t)row * N + col;
            float v = acc[i][j];
            if constexpr (EPI == EPI_TANH) {
                float t = tanhf(v + bias[col]);
                O1[idx] = t;
                O2[idx] = 1.f - t * t;
            } else if constexpr (EPI == EPI_BIAS) {
                O1[idx] = v + bias[col];
            } else if constexpr (EPI == EPI_MULS) {
                O1[idx] = v * Sp[idx];
            } else if constexpr (EPI == EPI_AXPY_SET) {
                float u = fmaf(alpha, v, ADD[idx]);
                O1[idx] = u;
                O2[idx] = u;
            } else {  // EPI_AXPY_ADD
                float u = alpha * v;
                O1[idx] = u;
                O2[idx] += u;
            }
        }
    }
}

extern "C" void kernel_launch(void* const* d_in, const int* in_sizes, int n_in,
                              void* d_out, int out_size, void* d_ws, size_t ws_size,
                              hipStream_t stream) {
    const float* Y  = (const float*)d_in[0];  // (512, 256)
    const float* W1 = (const float*)d_in[1];  // (1024, 256)
    const float* b1 = (const float*)d_in[2];  // (1024,)
    const float* W2 = (const float*)d_in[3];  // (256, 1024)
    const float* b2 = (const float*)d_in[4];  // (256,)
    float* OUT = (float*)d_out;               // (512, 256)

    float* ws = (float*)d_ws;
    float* T = ws;                       // (512,1024); reused as P after step 2
    float* S = T + B_SZ * HID_SZ;        // (512,1024)
    float* V = S + B_SZ * HID_SZ;        // (512,256)
    float* X = V + B_SZ * D_SZ;          // (512,256)
    float* P = T;                        // alias: T dead after step 2

    const float cc = 0.01f / 3.f;
    const float dd = 0.01f / 6.f;

    dim3 blk(256);
    dim3 g1(HID_SZ / 64, B_SZ / 64);  // (16,8) = 128 blocks, N=1024,K=256 GEMMs
    dim3 g2(D_SZ / 32, B_SZ / 32);    // (8,16) = 128 blocks, N=256,K=1024 GEMMs

    // 1. T = tanh(Y@W1^T + b1), S = 1 - T^2
    gemm_nt<EPI_TANH, 64, 64, 16, 4, 4><<<g1, blk, 0, stream>>>(
        Y, W1, B_SZ, HID_SZ, D_SZ, b1, nullptr, nullptr, 0.f, T, S);
    // 2. V = T@W2^T + b2
    gemm_nt<EPI_BIAS, 32, 32, 32, 2, 2><<<g2, blk, 0, stream>>>(
        T, W2, B_SZ, D_SZ, HID_SZ, b2, nullptr, nullptr, 0.f, V, nullptr);
    // 3. P = (V@W1^T) * S
    gemm_nt<EPI_MULS, 64, 64, 16, 4, 4><<<g1, blk, 0, stream>>>(
        V, W1, B_SZ, HID_SZ, D_SZ, nullptr, S, nullptr, 0.f, P, nullptr);
    // 4. U0 = V + dd*(P@W2^T);  X = U0; OUT = U0
    gemm_nt<EPI_AXPY_SET, 32, 32, 32, 2, 2><<<g2, blk, 0, stream>>>(
        P, W2, B_SZ, D_SZ, HID_SZ, nullptr, nullptr, V, dd, X, OUT);
    // 5. Neumann: 3x { X = cc*J@X; OUT += X }
    for (int it = 0; it < 3; ++it) {
        gemm_nt<EPI_MULS, 64, 64, 16, 4, 4><<<g1, blk, 0, stream>>>(
            X, W1, B_SZ, HID_SZ, D_SZ, nullptr, S, nullptr, 0.f, P, nullptr);
        gemm_nt<EPI_AXPY_ADD, 32, 32, 32, 2, 2><<<g2, blk, 0, stream>>>(
            P, W2, B_SZ, D_SZ, HID_SZ, nullptr, nullptr, nullptr, cc, X, OUT);
    }
}

// Round 2
// 117.520 us; speedup vs baseline: 3.5532x; 3.5532x over previous
//
#include <hip/hip_runtime.h>
#include <math.h>

// EulerRosenbrockModel: B=512, D=256, HID=1024, h=0.01
// out = v + (c+d) * J v, c=h/3, d=h/6  (Neumann-exact to ~7e-6 since ||cJ||~0.015)
// J = W2 diag(1-t^2) W1, t = tanh(W1 y + b1), v = W2 t + b2.
// 6 dispatches: G1 (T) -> G2 splitK (parts) -> C2 (V) -> G3 (P=(V@W1^T)*(1-T^2), aliases T)
//            -> G4 splitK (parts) -> C4 (OUT = V + 0.005*sum)

#define B_SZ   512
#define D_SZ   256
#define HID_SZ 1024
#define KSPLIT 4

enum { EPI_TANH = 0, EPI_DERIV = 1 };

// ---- shape A: C[512,1024] = A[512,256] @ W[1024,256]^T
// BM=32,BN=64,BK=32,TM=2,TN=4, 256 threads, grid (16,16) = 256 wg
template<int EPI>
__global__ __launch_bounds__(256)
void gemmA(const float* __restrict__ A, const float* __restrict__ W,
           const float* __restrict__ bias, const float* __restrict__ Tin,
           float* __restrict__ O)
{
    constexpr int N = HID_SZ, K = D_SZ;
    constexpr int BM = 32, BN = 64, BK = 32;
    __shared__ float As[BK][BM + 4];  // stride 36 floats = 144B (16B aligned)
    __shared__ float Bs[BK][BN + 4];  // stride 68 floats = 272B (16B aligned)
    const int bm = blockIdx.y * BM;
    const int bn = blockIdx.x * BN;
    const int tid = threadIdx.x;
    const int ty = tid >> 4;   // 0..15, m = ty*2
    const int tx = tid & 15;   // 0..15, n = tx*4

    const int ar = tid >> 3;          // 0..31 (A tile row)
    const int ak = (tid & 7) << 2;    // 0,4,..,28 (A tile k)

    float acc[2][4] = {{0.f,0.f,0.f,0.f},{0.f,0.f,0.f,0.f}};

    for (int k0 = 0; k0 < K; k0 += BK) {
        float4 av = *(const float4*)&A[(size_t)(bm + ar) * K + k0 + ak];
        As[ak + 0][ar] = av.x; As[ak + 1][ar] = av.y;
        As[ak + 2][ar] = av.z; As[ak + 3][ar] = av.w;
#pragma unroll
        for (int l = 0; l < 2; ++l) {
            int idx = l * 1024 + tid * 4;
            int r = idx >> 5, kc = idx & 31;
            float4 bv = *(const float4*)&W[(size_t)(bn + r) * K + k0 + kc];
            Bs[kc + 0][r] = bv.x; Bs[kc + 1][r] = bv.y;
            Bs[kc + 2][r] = bv.z; Bs[kc + 3][r] = bv.w;
        }
        __syncthreads();
#pragma unroll
        for (int kk = 0; kk < BK; ++kk) {
            float a0 = As[kk][ty * 2 + 0];
            float a1 = As[kk][ty * 2 + 1];
            float b0 = Bs[kk][tx * 4 + 0];
            float b1v = Bs[kk][tx * 4 + 1];
            float b2v = Bs[kk][tx * 4 + 2];
            float b3v = Bs[kk][tx * 4 + 3];
            acc[0][0] = fmaf(a0, b0,  acc[0][0]);
            acc[0][1] = fmaf(a0, b1v, acc[0][1]);
            acc[0][2] = fmaf(a0, b2v, acc[0][2]);
            acc[0][3] = fmaf(a0, b3v, acc[0][3]);
            acc[1][0] = fmaf(a1, b0,  acc[1][0]);
            acc[1][1] = fmaf(a1, b1v, acc[1][1]);
            acc[1][2] = fmaf(a1, b2v, acc[1][2]);
            acc[1][3] = fmaf(a1, b3v, acc[1][3]);
        }
        __syncthreads();
    }

#pragma unroll
    for (int i = 0; i < 2; ++i) {
        int row = bm + ty * 2 + i;
        size_t base = (size_t)row * N + bn + tx * 4;
        float4 o;
        if constexpr (EPI == EPI_TANH) {
            float4 bb = *(const float4*)&bias[bn + tx * 4];
            o.x = tanhf(acc[i][0] + bb.x);
            o.y = tanhf(acc[i][1] + bb.y);
            o.z = tanhf(acc[i][2] + bb.z);
            o.w = tanhf(acc[i][3] + bb.w);
        } else {
            float4 t = *(const float4*)&Tin[base];  // O may alias Tin: same addr, read-then-write in-thread
            o.x = acc[i][0] * (1.f - t.x * t.x);
            o.y = acc[i][1] * (1.f - t.y * t.y);
            o.z = acc[i][2] * (1.f - t.z * t.z);
            o.w = acc[i][3] * (1.f - t.w * t.w);
        }
        *(float4*)&O[base] = o;
    }
}

// ---- shape B (split-K): parts[z][512,256] = A[512, k-chunk] @ W[256, k-chunk]^T
// BM=32,BN=32,BK=32,TM=2,TN=2, 256 threads, grid (8,16,KSPLIT) = 512 wg
__global__ __launch_bounds__(256)
void gemmB(const float* __restrict__ A, const float* __restrict__ W,
           float* __restrict__ parts)
{
    constexpr int N = D_SZ, K = HID_SZ;
    constexpr int BM = 32, BN = 32, BK = 32;
    constexpr int KC = K / KSPLIT;  // 256
    __shared__ float As[BK][BM + 4];
    __shared__ float Bs[BK][BN + 4];
    const int bm = blockIdx.y * BM;
    const int bn = blockIdx.x * BN;
    const int kbase = blockIdx.z * KC;
    const int tid = threadIdx.x;
    const int ty = tid >> 4;   // m = ty*2
    const int tx = tid & 15;   // n = tx*2

    const int ar = tid >> 3;
    const int ak = (tid & 7) << 2;

    float acc[2][2] = {{0.f,0.f},{0.f,0.f}};

    for (int k0 = kbase; k0 < kbase + KC; k0 += BK) {
        float4 av = *(const float4*)&A[(size_t)(bm + ar) * K + k0 + ak];
        As[ak + 0][ar] = av.x; As[ak + 1][ar] = av.y;
        As[ak + 2][ar] = av.z; As[ak + 3][ar] = av.w;
        float4 bv = *(const float4*)&W[(size_t)(bn + ar) * K + k0 + ak];
        Bs[ak + 0][ar] = bv.x; Bs[ak + 1][ar] = bv.y;
        Bs[ak + 2][ar] = bv.z; Bs[ak + 3][ar] = bv.w;
        __syncthreads();
#pragma unroll
        for (int kk = 0; kk < BK; ++kk) {
            float a0 = As[kk][ty * 2 + 0];
            float a1 = As[kk][ty * 2 + 1];
            float b0 = Bs[kk][tx * 2 + 0];
            float b1v = Bs[kk][tx * 2 + 1];
            acc[0][0] = fmaf(a0, b0,  acc[0][0]);
            acc[0][1] = fmaf(a0, b1v, acc[0][1]);
            acc[1][0] = fmaf(a1, b0,  acc[1][0]);
            acc[1][1] = fmaf(a1, b1v, acc[1][1]);
        }
        __syncthreads();
    }

    float* dst = parts + (size_t)blockIdx.z * (B_SZ * D_SZ);
#pragma unroll
    for (int i = 0; i < 2; ++i) {
        int row = bm + ty * 2 + i;
        size_t base = (size_t)row * N + bn + tx * 2;
        *(float2*)&dst[base] = make_float2(acc[i][0], acc[i][1]);
    }
}

// C2: V = b2[col] + sum_z parts[z]   (float4, 32768 groups)
__global__ __launch_bounds__(256)
void combine2(const float* __restrict__ parts, const float* __restrict__ b2,
              float* __restrict__ V)
{
    int i = blockIdx.x * 256 + threadIdx.x;  // float4 index, 0..32767
    constexpr int P4 = (B_SZ * D_SZ) / 4;
    const float4* p = (const float4*)parts;
    float4 s0 = p[i];
    float4 s1 = p[i + P4];
    float4 s2 = p[i + 2 * P4];
    float4 s3 = p[i + 3 * P4];
    float4 bb = ((const float4*)b2)[i & 63];  // 64 float4 per row of 256
    float4 o;
    o.x = s0.x + s1.x + s2.x + s3.x + bb.x;
    o.y = s0.y + s1.y + s2.y + s3.y + bb.y;
    o.z = s0.z + s1.z + s2.z + s3.z + bb.z;
    o.w = s0.w + s1.w + s2.w + s3.w + bb.w;
    ((float4*)V)[i] = o;
}

// C4: OUT = V + alpha * sum_z parts[z]
__global__ __launch_bounds__(256)
void combine4(const float* __restrict__ parts, const float* __restrict__ V,
              float* __restrict__ OUT, float alpha)
{
    int i = blockIdx.x * 256 + threadIdx.x;
    constexpr int P4 = (B_SZ * D_SZ) / 4;
    const float4* p = (const float4*)parts;
    float4 s0 = p[i];
    float4 s1 = p[i + P4];
    float4 s2 = p[i + 2 * P4];
    float4 s3 = p[i + 3 * P4];
    float4 vv = ((const float4*)V)[i];
    float4 o;
    o.x = fmaf(alpha, s0.x + s1.x + s2.x + s3.x, vv.x);
    o.y = fmaf(alpha, s0.y + s1.y + s2.y + s3.y, vv.y);
    o.z = fmaf(alpha, s0.z + s1.z + s2.z + s3.z, vv.z);
    o.w = fmaf(alpha, s0.w + s1.w + s2.w + s3.w, vv.w);
    ((float4*)OUT)[i] = o;
}

extern "C" void kernel_launch(void* const* d_in, const int* in_sizes, int n_in,
                              void* d_out, int out_size, void* d_ws, size_t ws_size,
                              hipStream_t stream) {
    const float* Y  = (const float*)d_in[0];  // (512, 256)
    const float* W1 = (const float*)d_in[1];  // (1024, 256)
    const float* b1 = (const float*)d_in[2];  // (1024,)
    const float* W2 = (const float*)d_in[3];  // (256, 1024)
    const float* b2 = (const float*)d_in[4];  // (256,)
    float* OUT = (float*)d_out;               // (512, 256)

    float* ws = (float*)d_ws;
    float* T     = ws;                          // (512,1024) ; aliased by P after G3
    float* V     = T + B_SZ * HID_SZ;           // (512,256)
    float* parts = V + B_SZ * D_SZ;             // KSPLIT x (512,256)
    // total: 524288 + 131072 + 524288 floats = 4.72 MB

    const float cd = 0.01f / 3.f + 0.01f / 6.f;  // 0.005

    dim3 blk(256);
    dim3 gA(HID_SZ / 64, B_SZ / 32);          // (16,16) = 256 wg
    dim3 gB(D_SZ / 32, B_SZ / 32, KSPLIT);    // (8,16,4) = 512 wg
    dim3 gC((B_SZ * D_SZ / 4) / 256);         // 128 wg

    // 1. T = tanh(Y@W1^T + b1)
    gemmA<EPI_TANH><<<gA, blk, 0, stream>>>(Y, W1, b1, nullptr, T);
    // 2. parts[z] = T@W2^T (k-chunks)
    gemmB<<<gB, blk, 0, stream>>>(T, W2, parts);
    // 3. V = sum parts + b2
    combine2<<<gC, blk, 0, stream>>>(parts, b2, V);
    // 4. P = (V@W1^T) * (1 - T^2), written over T
    gemmA<EPI_DERIV><<<gA, blk, 0, stream>>>(V, W1, nullptr, T, T);
    // 5. parts[z] = P@W2^T
    gemmB<<<gB, blk, 0, stream>>>(T, W2, parts);
    // 6. OUT = V + 0.005 * sum parts
    combine4<<<gC, blk, 0, stream>>>(parts, V, OUT, cd);
}

// Round 3
// 109.011 us; speedup vs baseline: 3.8305x; 1.0781x over previous
//
#include <hip/hip_runtime.h>
#include <math.h>

// EulerRosenbrockModel: B=512, D=256, HID=1024, h=0.01
// out_b = v_b + 0.005 * W2 (s_b ⊙ (W1 v_b)),  s_b = 1 - t_b^2,
// t_b = tanh(W1 y_b + b1), v_b = W2 t_b + b2.
// (Neumann truncation of (I-cJ)^{-1}(I+dJ); exact to ~1e-5, verified R1/R2.)
//
// Row-independent per batch sample -> fused per-row kernel, 2 rows/block,
// 256 blocks (1/CU). Weights pre-transposed + bf16 (one prep dispatch) so the
// fused kernel streams 2 MB/block of coalesced bf16x4 with fp32 accumulate.

#define B_SZ   512
#define D_SZ   256
#define HID_SZ 1024

__device__ __forceinline__ float bf16_to_f32(unsigned short u) {
    union { unsigned int i; float f; } c; c.i = ((unsigned int)u) << 16; return c.f;
}
__device__ __forceinline__ unsigned short f32_to_bf16(float f) {
    union { float f; unsigned int i; } c; c.f = f;
    unsigned int b = c.i + 0x7FFFu + ((c.i >> 16) & 1u);   // round-to-nearest-even
    return (unsigned short)(b >> 16);
}

// One dispatch: W1 [1024,256] -> W1t [256][1024] bf16 ; W2 [256,1024] -> W2t [1024][256] bf16.
__global__ __launch_bounds__(256)
void transpose_bf16(const float* __restrict__ W1, const float* __restrict__ W2,
                    unsigned short* __restrict__ W1t, unsigned short* __restrict__ W2t)
{
    __shared__ float tile[32][33];
    int b = blockIdx.x;
    const float* src; unsigned short* dst; int Rr, Cc, by, bx;
    if (b < 256) { src = W1; dst = W1t; Rr = 1024; Cc = 256;  by = b >> 3; bx = b & 7;  }
    else { b -= 256; src = W2; dst = W2t; Rr = 256;  Cc = 1024; by = b >> 5; bx = b & 31; }
    const int tid = threadIdx.x;
    const int lr = tid >> 3, lc = (tid & 7) * 4;
    float4 v = *(const float4*)&src[(size_t)(by * 32 + lr) * Cc + bx * 32 + lc];
    tile[lr][lc + 0] = v.x; tile[lr][lc + 1] = v.y;
    tile[lr][lc + 2] = v.z; tile[lr][lc + 3] = v.w;
    __syncthreads();
    const int wr = tid >> 3, wc4 = (tid & 7) * 4;
    ushort4 o;
    o.x = f32_to_bf16(tile[wc4 + 0][wr]);
    o.y = f32_to_bf16(tile[wc4 + 1][wr]);
    o.z = f32_to_bf16(tile[wc4 + 2][wr]);
    o.w = f32_to_bf16(tile[wc4 + 3][wr]);
    *(ushort4*)&dst[(size_t)(bx * 32 + wr) * Rr + by * 32 + wc4] = o;
}

// Fused per-row kernel: 256 blocks x 256 threads, 2 batch rows per block.
__global__ __launch_bounds__(256)
void fused_rows(const float* __restrict__ Y,
                const unsigned short* __restrict__ W1t,  // [256][1024] = W1^T
                const unsigned short* __restrict__ W2t,  // [1024][256] = W2^T
                const float* __restrict__ b1, const float* __restrict__ b2,
                float* __restrict__ OUT)
{
    __shared__ float yb[2][256];     // 2 KB
    __shared__ float tb[2][1024];    // 8 KB   tanh values
    __shared__ float vb[2][256];     // 2 KB   v = W2 t + b2
    __shared__ float pb[2][1024];    // 8 KB   p = s ⊙ (W1 v)
    __shared__ float4 red[4][2][64]; // 8 KB   split-K partials (stages 2 & 4)
    const int tid = threadIdx.x;
    const int r0 = blockIdx.x * 2;

    // load y rows (fp32)
    {
        int idx = tid * 2;
        int row = idx >> 8, k = idx & 255;
        *(float2*)&yb[row][k] = *(const float2*)&Y[(size_t)(r0 + row) * D_SZ + k];
    }
    __syncthreads();

    // ---- stage 1: t = tanh(W1 y + b1)   (thread owns 4 consecutive j)
    {
        const int j4 = tid * 4;
        float4 a0 = {0.f,0.f,0.f,0.f}, a1 = {0.f,0.f,0.f,0.f};
#pragma unroll 8
        for (int k = 0; k < 256; ++k) {
            ushort4 w = *(const ushort4*)&W1t[(size_t)k * HID_SZ + j4];
            float f0 = bf16_to_f32(w.x), f1 = bf16_to_f32(w.y);
            float f2 = bf16_to_f32(w.z), f3 = bf16_to_f32(w.w);
            float y0 = yb[0][k], y1 = yb[1][k];
            a0.x = fmaf(f0, y0, a0.x); a0.y = fmaf(f1, y0, a0.y);
            a0.z = fmaf(f2, y0, a0.z); a0.w = fmaf(f3, y0, a0.w);
            a1.x = fmaf(f0, y1, a1.x); a1.y = fmaf(f1, y1, a1.y);
            a1.z = fmaf(f2, y1, a1.z); a1.w = fmaf(f3, y1, a1.w);
        }
        float4 bb = *(const float4*)&b1[j4];
        float4 t0, t1;
        t0.x = tanhf(a0.x + bb.x); t0.y = tanhf(a0.y + bb.y);
        t0.z = tanhf(a0.z + bb.z); t0.w = tanhf(a0.w + bb.w);
        t1.x = tanhf(a1.x + bb.x); t1.y = tanhf(a1.y + bb.y);
        t1.z = tanhf(a1.z + bb.z); t1.w = tanhf(a1.w + bb.w);
        *(float4*)&tb[0][j4] = t0;
        *(float4*)&tb[1][j4] = t1;
    }
    __syncthreads();

    // ---- stage 2: v = W2 t + b2   (split K=1024 into 4 chunks of 256)
    {
        const int jc = tid >> 6, ig = tid & 63, i4 = ig * 4;
        float4 a0 = {0.f,0.f,0.f,0.f}, a1 = {0.f,0.f,0.f,0.f};
#pragma unroll 8
        for (int jj = 0; jj < 256; ++jj) {
            int j = jc * 256 + jj;
            ushort4 w = *(const ushort4*)&W2t[(size_t)j * D_SZ + i4];
            float f0 = bf16_to_f32(w.x), f1 = bf16_to_f32(w.y);
            float f2 = bf16_to_f32(w.z), f3 = bf16_to_f32(w.w);
            float t0 = tb[0][j], t1 = tb[1][j];
            a0.x = fmaf(f0, t0, a0.x); a0.y = fmaf(f1, t0, a0.y);
            a0.z = fmaf(f2, t0, a0.z); a0.w = fmaf(f3, t0, a0.w);
            a1.x = fmaf(f0, t1, a1.x); a1.y = fmaf(f1, t1, a1.y);
            a1.z = fmaf(f2, t1, a1.z); a1.w = fmaf(f3, t1, a1.w);
        }
        red[jc][0][ig] = a0;
        red[jc][1][ig] = a1;
    }
    __syncthreads();
    {   // reduce 4 partials + b2 -> vb
        const float* rf = (const float*)red;
        int o = tid * 2;
        int row = o >> 8, i = o & 255;
        float s0 = rf[(0 * 2 + row) * 256 + i] + rf[(1 * 2 + row) * 256 + i]
                 + rf[(2 * 2 + row) * 256 + i] + rf[(3 * 2 + row) * 256 + i];
        float s1 = rf[(0 * 2 + row) * 256 + i + 1] + rf[(1 * 2 + row) * 256 + i + 1]
                 + rf[(2 * 2 + row) * 256 + i + 1] + rf[(3 * 2 + row) * 256 + i + 1];
        float2 bb = *(const float2*)&b2[i];
        vb[row][i]     = s0 + bb.x;
        vb[row][i + 1] = s1 + bb.y;
    }
    __syncthreads();

    // ---- stage 3: p = (1 - t^2) ⊙ (W1 v)   (no bias)
    {
        const int j4 = tid * 4;
        float4 a0 = {0.f,0.f,0.f,0.f}, a1 = {0.f,0.f,0.f,0.f};
#pragma unroll 8
        for (int k = 0; k < 256; ++k) {
            ushort4 w = *(const ushort4*)&W1t[(size_t)k * HID_SZ + j4];
            float f0 = bf16_to_f32(w.x), f1 = bf16_to_f32(w.y);
            float f2 = bf16_to_f32(w.z), f3 = bf16_to_f32(w.w);
            float v0 = vb[0][k], v1 = vb[1][k];
            a0.x = fmaf(f0, v0, a0.x); a0.y = fmaf(f1, v0, a0.y);
            a0.z = fmaf(f2, v0, a0.z); a0.w = fmaf(f3, v0, a0.w);
            a1.x = fmaf(f0, v1, a1.x); a1.y = fmaf(f1, v1, a1.y);
            a1.z = fmaf(f2, v1, a1.z); a1.w = fmaf(f3, v1, a1.w);
        }
        float4 t0 = *(const float4*)&tb[0][j4];
        float4 t1 = *(const float4*)&tb[1][j4];
        float4 p0, p1;
        p0.x = a0.x * (1.f - t0.x * t0.x); p0.y = a0.y * (1.f - t0.y * t0.y);
        p0.z = a0.z * (1.f - t0.z * t0.z); p0.w = a0.w * (1.f - t0.w * t0.w);
        p1.x = a1.x * (1.f - t1.x * t1.x); p1.y = a1.y * (1.f - t1.y * t1.y);
        p1.z = a1.z * (1.f - t1.z * t1.z); p1.w = a1.w * (1.f - t1.w * t1.w);
        *(float4*)&pb[0][j4] = p0;
        *(float4*)&pb[1][j4] = p1;
    }
    __syncthreads();

    // ---- stage 4: OUT = v + 0.005 * W2 p   (split-K like stage 2)
    {
        const int jc = tid >> 6, ig = tid & 63, i4 = ig * 4;
        float4 a0 = {0.f,0.f,0.f,0.f}, a1 = {0.f,0.f,0.f,0.f};
#pragma unroll 8
        for (int jj = 0; jj < 256; ++jj) {
            int j = jc * 256 + jj;
            ushort4 w = *(const ushort4*)&W2t[(size_t)j * D_SZ + i4];
            float f0 = bf16_to_f32(w.x), f1 = bf16_to_f32(w.y);
            float f2 = bf16_to_f32(w.z), f3 = bf16_to_f32(w.w);
            float p0 = pb[0][j], p1 = pb[1][j];
            a0.x = fmaf(f0, p0, a0.x); a0.y = fmaf(f1, p0, a0.y);
            a0.z = fmaf(f2, p0, a0.z); a0.w = fmaf(f3, p0, a0.w);
            a1.x = fmaf(f0, p1, a1.x); a1.y = fmaf(f1, p1, a1.y);
            a1.z = fmaf(f2, p1, a1.z); a1.w = fmaf(f3, p1, a1.w);
        }
        red[jc][0][ig] = a0;
        red[jc][1][ig] = a1;
    }
    __syncthreads();
    {   // reduce + epilogue -> global OUT
        const float* rf = (const float*)red;
        int o = tid * 2;
        int row = o >> 8, i = o & 255;
        float s0 = rf[(0 * 2 + row) * 256 + i] + rf[(1 * 2 + row) * 256 + i]
                 + rf[(2 * 2 + row) * 256 + i] + rf[(3 * 2 + row) * 256 + i];
        float s1 = rf[(0 * 2 + row) * 256 + i + 1] + rf[(1 * 2 + row) * 256 + i + 1]
                 + rf[(2 * 2 + row) * 256 + i + 1] + rf[(3 * 2 + row) * 256 + i + 1];
        float2 o2;
        o2.x = fmaf(0.005f, s0, vb[row][i]);
        o2.y = fmaf(0.005f, s1, vb[row][i + 1]);
        *(float2*)&OUT[(size_t)(r0 + row) * D_SZ + i] = o2;
    }
}

extern "C" void kernel_launch(void* const* d_in, const int* in_sizes, int n_in,
                              void* d_out, int out_size, void* d_ws, size_t ws_size,
                              hipStream_t stream) {
    const float* Y  = (const float*)d_in[0];  // (512, 256)
    const float* W1 = (const float*)d_in[1];  // (1024, 256)
    const float* b1 = (const float*)d_in[2];  // (1024,)
    const float* W2 = (const float*)d_in[3];  // (256, 1024)
    const float* b2 = (const float*)d_in[4];  // (256,)
    float* OUT = (float*)d_out;               // (512, 256)

    unsigned short* W1t = (unsigned short*)d_ws;            // [256][1024] bf16, 512 KB
    unsigned short* W2t = W1t + D_SZ * HID_SZ;              // [1024][256] bf16, 512 KB

    transpose_bf16<<<512, 256, 0, stream>>>(W1, W2, W1t, W2t);
    fused_rows<<<256, 256, 0, stream>>>(Y, W1t, W2t, b1, b2, OUT);
}

// Round 4
// 82.690 us; speedup vs baseline: 5.0498x; 1.3183x over previous
//
#include <hip/hip_runtime.h>
#include <math.h>

// EulerRosenbrockModel: B=512, D=256, HID=1024, h=0.01
// out = v + 0.005 * W2 (s ⊙ (W1 v)),  s = 1-t^2, t = tanh(W1 y + b1), v = W2 t + b2
// (Neumann truncation of (I-cJ)^{-1}(I+dJ), exact to ~1e-5 — verified R1-R3.)
//
// 5 dispatches, all bf16 MFMA 16x16x32, fp32 accumulate:
//   prep:  Y,W1,W2 fp32 -> bf16 (no transpose; NT GEMM reads rows k-contiguous)
//   G1:    Tb = tanh(Y@W1^T + b1)              M=512 N=1024 K=256  (bf16 out)
//   G2:    Vf = Tb@W2^T + b2 ; Vb = bf16(Vf)   M=512 N=256  K=1024 (wave-split-K)
//   G3:    Pb = (1-Tb^2) ⊙ (Vb@W1^T)           M=512 N=1024 K=256
//   G4:    OUT = Vf + 0.005 * (Pb@W2^T)        M=512 N=256  K=1024
// Every GEMM launches 256 blocks (1/CU).

#define B_SZ 512
#define D_SZ 256
#define HID_SZ 1024

typedef short short8 __attribute__((ext_vector_type(8)));   // 8 bf16 (4 VGPRs)
typedef float f32x4 __attribute__((ext_vector_type(4)));

__device__ __forceinline__ float bf16_to_f32(unsigned short u) {
    union { unsigned int i; float f; } c; c.i = ((unsigned int)u) << 16; return c.f;
}
__device__ __forceinline__ unsigned short f32_to_bf16(float f) {
    union { float f; unsigned int i; } c; c.f = f;
    unsigned int b = c.i + 0x7FFFu + ((c.i >> 16) & 1u);   // RNE
    return (unsigned short)(b >> 16);
}

// ---- prep: fp32 -> bf16 for Y (131072), W1 (262144), W2 (262144), contiguous dst.
__global__ __launch_bounds__(256)
void prep_bf16(const float* __restrict__ Y, const float* __restrict__ W1,
               const float* __restrict__ W2, unsigned short* __restrict__ dst)
{
    int i8 = (blockIdx.x * 256 + threadIdx.x) * 8;
    const float* src; int off;
    if (i8 < 131072)      { src = Y;  off = i8; }
    else if (i8 < 393216) { src = W1; off = i8 - 131072; }
    else                  { src = W2; off = i8 - 393216; }
    float4 a = *(const float4*)&src[off];
    float4 b = *(const float4*)&src[off + 4];
    union { unsigned short u[8]; uint4 v; } o;
    o.u[0] = f32_to_bf16(a.x); o.u[1] = f32_to_bf16(a.y);
    o.u[2] = f32_to_bf16(a.z); o.u[3] = f32_to_bf16(a.w);
    o.u[4] = f32_to_bf16(b.x); o.u[5] = f32_to_bf16(b.y);
    o.u[6] = f32_to_bf16(b.z); o.u[7] = f32_to_bf16(b.w);
    *(uint4*)&dst[i8] = o.v;
}

// ---- G1/G3: C[512,1024] = A[512,256] @ W[1024,256]^T, tiles 32x64, grid (16,16)=256.
// 4 waves in 2x2; wave = 16x32 = 2 MFMA tiles; K-loop 4 iters of BK=64.
enum { EPI_T = 0, EPI_P = 1 };
template<int EPI>
__global__ __launch_bounds__(256)
void gemm_h(const unsigned short* __restrict__ Ab,   // [512][256] bf16 (Yb or Vb)
            const unsigned short* __restrict__ Wb,   // [1024][256] bf16 (W1b)
            const float* __restrict__ b1,
            const unsigned short* __restrict__ Tin,  // EPI_P: [512][1024] bf16
            unsigned short* __restrict__ Ob)         // [512][1024] bf16
{
    __shared__ alignas(16) unsigned short As[32][72];  // +8 pad: 144B stride, 2-way max
    __shared__ alignas(16) unsigned short Bs[64][72];
    const int tid = threadIdx.x;
    const int bm = blockIdx.x * 32;
    const int bn = blockIdx.y * 64;
    const int wid = tid >> 6, lane = tid & 63;
    const int l16 = lane & 15, quad = lane >> 4;
    const int wm = wid >> 1, wn = wid & 1;

    f32x4 acc0 = {0.f, 0.f, 0.f, 0.f}, acc1 = {0.f, 0.f, 0.f, 0.f};
    const int arow = tid >> 3, acol = (tid & 7) * 8;

    for (int k0 = 0; k0 < 256; k0 += 64) {
        *(uint4*)&As[arow][acol] = *(const uint4*)&Ab[(size_t)(bm + arow) * 256 + k0 + acol];
#pragma unroll
        for (int r = 0; r < 2; ++r) {
            int u = r * 256 + tid;
            int brow = u >> 3, bcol = (u & 7) * 8;
            *(uint4*)&Bs[brow][bcol] = *(const uint4*)&Wb[(size_t)(bn + brow) * 256 + k0 + bcol];
        }
        __syncthreads();
#pragma unroll
        for (int ks = 0; ks < 64; ks += 32) {
            short8 a  = *(const short8*)&As[wm * 16 + l16][ks + quad * 8];
            short8 b0 = *(const short8*)&Bs[wn * 32 + l16][ks + quad * 8];
            short8 b1f = *(const short8*)&Bs[wn * 32 + 16 + l16][ks + quad * 8];
            acc0 = __builtin_amdgcn_mfma_f32_16x16x32_bf16(a, b0, acc0, 0, 0, 0);
            acc1 = __builtin_amdgcn_mfma_f32_16x16x32_bf16(a, b1f, acc1, 0, 0, 0);
        }
        __syncthreads();
    }
    // epilogue: C/D layout col=lane&15, row=quad*4+reg
#pragma unroll
    for (int t2 = 0; t2 < 2; ++t2) {
        f32x4 acc = t2 ? acc1 : acc0;
        int col = bn + wn * 32 + t2 * 16 + l16;
        float bias = (EPI == EPI_T) ? b1[col] : 0.f;
#pragma unroll
        for (int r = 0; r < 4; ++r) {
            int row = bm + wm * 16 + quad * 4 + r;
            float v = acc[r];
            float o;
            if constexpr (EPI == EPI_T) {
                o = tanhf(v + bias);
            } else {
                float tt = bf16_to_f32(Tin[(size_t)row * 1024 + col]);
                o = v * (1.f - tt * tt);
            }
            Ob[(size_t)row * 1024 + col] = f32_to_bf16(o);
        }
    }
}

// ---- G2/G4: C[512,256] = A[512,1024] @ W[256,1024]^T, tiles 16x32, grid (32,8)=256.
// Wave w owns K chunk [w*256, +256); per k-iter stage 4 chunks of BK=64; LDS-reduce.
enum { EPI_V = 0, EPI_O = 1 };
template<int EPI>
__global__ __launch_bounds__(256)
void gemm_d(const unsigned short* __restrict__ Ab,   // [512][1024] bf16 (Tb or Pb)
            const unsigned short* __restrict__ Wb,   // [256][1024] bf16 (W2b)
            const float* __restrict__ b2,
            const float* __restrict__ Vf_in,         // EPI_O
            float* __restrict__ Vf_out,              // EPI_V
            unsigned short* __restrict__ Vb_out,     // EPI_V
            float* __restrict__ OUT)                 // EPI_O
{
    __shared__ alignas(16) unsigned short As[4][16][72];
    __shared__ alignas(16) unsigned short Bs[4][32][72];
    __shared__ alignas(16) float red[4][16][34];  // stride 34: 8B-aligned float2 rows
    const int tid = threadIdx.x;
    const int bm = blockIdx.x * 16;
    const int bn = blockIdx.y * 32;
    const int wid = tid >> 6, lane = tid & 63;
    const int l16 = lane & 15, quad = lane >> 4;

    f32x4 acc0 = {0.f, 0.f, 0.f, 0.f}, acc1 = {0.f, 0.f, 0.f, 0.f};

    for (int i = 0; i < 4; ++i) {
#pragma unroll
        for (int r = 0; r < 2; ++r) {  // A: 4 chunks x 16 rows x 8 units
            int u = r * 256 + tid;
            int c = u >> 7, rem = u & 127;
            int row = rem >> 3, col = (rem & 7) * 8;
            *(uint4*)&As[c][row][col] =
                *(const uint4*)&Ab[(size_t)(bm + row) * 1024 + c * 256 + i * 64 + col];
        }
#pragma unroll
        for (int r = 0; r < 4; ++r) {  // B: 4 chunks x 32 rows x 8 units
            int u = r * 256 + tid;
            int c = u >> 8, rem = u & 255;
            int row = rem >> 3, col = (rem & 7) * 8;
            *(uint4*)&Bs[c][row][col] =
                *(const uint4*)&Wb[(size_t)(bn + row) * 1024 + c * 256 + i * 64 + col];
        }
        __syncthreads();
#pragma unroll
        for (int ks = 0; ks < 64; ks += 32) {
            short8 a  = *(const short8*)&As[wid][l16][ks + quad * 8];
            short8 b0 = *(const short8*)&Bs[wid][l16][ks + quad * 8];
            short8 b1f = *(const short8*)&Bs[wid][16 + l16][ks + quad * 8];
            acc0 = __builtin_amdgcn_mfma_f32_16x16x32_bf16(a, b0, acc0, 0, 0, 0);
            acc1 = __builtin_amdgcn_mfma_f32_16x16x32_bf16(a, b1f, acc1, 0, 0, 0);
        }
        __syncthreads();
    }
    // cross-wave K reduction via LDS
#pragma unroll
    for (int r = 0; r < 4; ++r) {
        red[wid][quad * 4 + r][l16]      = acc0[r];
        red[wid][quad * 4 + r][16 + l16] = acc1[r];
    }
    __syncthreads();
    {
        int m = tid >> 4, n = (tid & 15) * 2;   // 512 elems, 2/thread
        float2 s = {0.f, 0.f};
#pragma unroll
        for (int w = 0; w < 4; ++w) {
            float2 p = *(const float2*)&red[w][m][n];
            s.x += p.x; s.y += p.y;
        }
        int gm = bm + m, gn = bn + n;
        size_t idx = (size_t)gm * 256 + gn;
        if constexpr (EPI == EPI_V) {
            float2 bb = *(const float2*)&b2[gn];
            float2 v = {s.x + bb.x, s.y + bb.y};
            *(float2*)&Vf_out[idx] = v;
            Vb_out[idx]     = f32_to_bf16(v.x);
            Vb_out[idx + 1] = f32_to_bf16(v.y);
        } else {
            float2 vv = *(const float2*)&Vf_in[idx];
            float2 o = {fmaf(0.005f, s.x, vv.x), fmaf(0.005f, s.y, vv.y)};
            *(float2*)&OUT[idx] = o;
        }
    }
}

extern "C" void kernel_launch(void* const* d_in, const int* in_sizes, int n_in,
                              void* d_out, int out_size, void* d_ws, size_t ws_size,
                              hipStream_t stream) {
    const float* Y  = (const float*)d_in[0];  // (512, 256)
    const float* W1 = (const float*)d_in[1];  // (1024, 256)
    const float* b1 = (const float*)d_in[2];  // (1024,)
    const float* W2 = (const float*)d_in[3];  // (256, 1024)
    const float* b2 = (const float*)d_in[4];  // (256,)
    float* OUT = (float*)d_out;               // (512, 256)

    unsigned short* wsu = (unsigned short*)d_ws;
    unsigned short* Yb  = wsu;                 // [512][256]   131072
    unsigned short* W1b = wsu + 131072;        // [1024][256]  262144
    unsigned short* W2b = wsu + 393216;        // [256][1024]  262144
    unsigned short* Tb  = wsu + 655360;        // [512][1024]  524288
    unsigned short* Pb  = wsu + 1179648;       // [512][1024]  524288
    float*          Vf  = (float*)(wsu + 1703936);   // [512][256] fp32
    unsigned short* Vb  = wsu + 1966080;       // [512][256] bf16

    prep_bf16<<<320, 256, 0, stream>>>(Y, W1, W2, wsu);
    gemm_h<EPI_T><<<dim3(16, 16), 256, 0, stream>>>(Yb, W1b, b1, nullptr, Tb);
    gemm_d<EPI_V><<<dim3(32, 8), 256, 0, stream>>>(Tb, W2b, b2, nullptr, Vf, Vb, nullptr);
    gemm_h<EPI_P><<<dim3(16, 16), 256, 0, stream>>>(Vb, W1b, nullptr, Tb, Pb);
    gemm_d<EPI_O><<<dim3(32, 8), 256, 0, stream>>>(Pb, W2b, nullptr, Vf, nullptr, nullptr, OUT);
}